// Round 6
// baseline (266.207 us; speedup 1.0000x reference)
//
#include <hip/hip_runtime.h>
#include <cstdint>
#include <cstddef>

// Problem constants
#define B_    2
#define S_    2048
#define HQ_   32
#define HKV_  8
#define D_    128
#define QSCALE_ (0.08838834764831845f * 1.4426950408889634f)  // fold log2(e): softmax in base 2

#define NROW_ (B_*S_*HKV_)   // 32768 rows per tensor

typedef __bf16 bf16x8 __attribute__((ext_vector_type(8)));
typedef float  f32x4  __attribute__((ext_vector_type(4)));

__device__ __forceinline__ unsigned short f2bfu(float f) {
    __bf16 b = (__bf16)f;           // RTNE
    return __builtin_bit_cast(unsigned short, b);
}

// async 16B/lane global->LDS; lds base must be wave-uniform (HW adds lane*16)
__device__ __forceinline__ void gl_lds16(const unsigned short* g, unsigned short* l) {
    __builtin_amdgcn_global_load_lds(
        (const __attribute__((address_space(1))) void*)g,
        (__attribute__((address_space(3))) void*)l, 16, 0, 0);
}

// Emulate reference quant_dequant_e4m3 exactly, branch/libcall-free.
__device__ __forceinline__ float qd_e4m3(float x) {
    float ax = fabsf(x);
    float xc = fminf(fmaxf(x, -448.f), 448.f);
    float axc = fmaxf(ax, 1e-12f);
    int e = (int)((__builtin_bit_cast(unsigned int, axc) >> 23) & 255u) - 127;
    e = min(max(e, -6), 8);
    float s1 = __builtin_bit_cast(float, (unsigned int)(130 - e) << 23); // 2^(3-e)
    float s2 = __builtin_bit_cast(float, (unsigned int)(124 + e) << 23); // 2^(e-3)
    float q = rintf(xc * s1) * s2;
    return ax == 0.f ? 0.f : q;
}

// fp4 e2m1 quant-dequant; searchsorted 'left' => ties at midpoints go DOWN
__device__ __forceinline__ float qd_fp4(float x, float scale) {
    float xn = x / scale;                    // IEEE div, matches numpy
    float a = fabsf(xn);
    float g;
    if      (a <= 0.25f) g = 0.f;
    else if (a <= 0.75f) g = 0.5f;
    else if (a <= 1.25f) g = 1.f;
    else if (a <= 1.75f) g = 1.5f;
    else if (a <= 2.5f)  g = 2.f;
    else if (a <= 3.5f)  g = 3.f;
    else if (a <= 5.f)   g = 4.f;
    else                 g = 6.f;
    return copysignf(g * scale, xn);
}

// Kernel 1: quantize K and V -> bf16 dequantized, [b][hkv][s][d] layout.
// One wave per row; 2 elems/lane (round-3/5-proven version — do not touch).
__global__ __launch_bounds__(256) void quant_kv(const float* __restrict__ k,
                                                const float* __restrict__ v,
                                                unsigned short* __restrict__ kd,
                                                unsigned short* __restrict__ vd) {
    int gw = (blockIdx.x * 256 + threadIdx.x) >> 6;  // global wave id
    int lane = threadIdx.x & 63;
    int row = gw;
    const float* src;
    unsigned short* dst;
    if (row < NROW_) { src = k; dst = kd; }
    else             { row -= NROW_; src = v; dst = vd; }
    int b   = row / (S_ * HKV_);
    int rem = row - b * (S_ * HKV_);
    int s   = rem >> 3;      // HKV = 8
    int h   = rem & 7;
    float2 x = *(const float2*)(src + (size_t)row * D_ + 2 * lane);
    float q0 = qd_e4m3(x.x);
    float q1 = qd_e4m3(x.y);
    float amax = fmaxf(fabsf(q0), fabsf(q1));
#pragma unroll
    for (int m = 1; m < 64; m <<= 1) amax = fmaxf(amax, __shfl_xor(amax, m, 64));
    float scale = fmaxf(amax / 6.0f, 1e-12f);
    float y0 = qd_fp4(q0, scale);
    float y1 = qd_fp4(q1, scale);
    size_t outOff = ((size_t)(b * HKV_ + h) * S_ + s) * D_ + 2 * lane;
    unsigned int pack = (unsigned int)f2bfu(y0) | ((unsigned int)f2bfu(y1) << 16);
    *(unsigned int*)(dst + outOff) = pack;
}

// Kernel 2: transpose V to [b][hkv][d][s]
__global__ __launch_bounds__(256) void transpose_v(const unsigned short* __restrict__ vd,
                                                   unsigned short* __restrict__ vdT) {
    __shared__ alignas(16) unsigned short t[64][136];  // +8 pad
    int bh = blockIdx.x >> 5;       // b*HKV + h
    int st = blockIdx.x & 31;
    int s0 = st * 64;
    int tid = threadIdx.x;
    {
        int row = tid >> 2;
        const unsigned short* sp = vd + ((size_t)bh * S_ + s0 + row) * D_;
#pragma unroll
        for (int i = 0; i < 4; ++i) {
            int c = (tid & 3) + 4 * i;
            *(uint4*)&t[row][c * 8] = *(const uint4*)(sp + c * 8);
        }
    }
    __syncthreads();
    {
        int d = tid >> 1;
        unsigned short* dp = vdT + ((size_t)bh * D_ + d) * S_ + s0;
#pragma unroll
        for (int i = 0; i < 4; ++i) {
            int c = (tid & 1) + 2 * i;
            int so = c * 8;
            unsigned short tmp[8];
#pragma unroll
            for (int e = 0; e < 8; ++e) tmp[e] = t[so + e][d];
            *(uint4*)(dp + so) = *(uint4*)tmp;
        }
    }
}

// Kernel 3: causal GQA flash attention. Round-5 structure, but each wave owns
// 32 queries (two 16-row subtiles) so every K/V ds_read_b128 feeds TWO MFMAs
// (the LDS-read pipe was ~60% of round-5's attn time). Block = 128 queries of
// one (b,hq); grid 64 x 8 pairs (15-yp, yp) => 34 64-key tile-units/block,
// 512 blocks = exactly 2/CU (LDS 48 KB). Fixed-M softmax (exact), l via
// ones-column MFMA — both round-5-proven.
__global__ __launch_bounds__(256) void attn(const float* __restrict__ q,
                                            const unsigned short* __restrict__ kd,
                                            const unsigned short* __restrict__ vdT,
                                            float* __restrict__ out) {
    int bh = blockIdx.x;           // 0..63
    int yp = blockIdx.y;           // 0..7
    int b  = bh >> 5;
    int hq = bh & 31;
    int hkv = hq >> 2;             // GQA group of 4
    int tid  = threadIdx.x;
    int lane = tid & 63;
    int wave = tid >> 6;
    int m16  = lane & 15;
    int g    = lane >> 4;
    int m8   = m16 & 7;

    __shared__ alignas(16) unsigned short ks[64 * 128];    // K [key][d], swz ^(key&15) on 16B
    __shared__ alignas(16) unsigned short vs[128 * 64];    // V^T [d][key], swz ^(d&7) on 16B
    __shared__ alignas(16) unsigned short ps[8 * 16 * 64]; // per-subtile P [q][key], swz ^(q&7)

    const unsigned short* kbase = kd  + (size_t)(b * HKV_ + hkv) * S_ * D_;
    const unsigned short* vbase = vdT + (size_t)(b * HKV_ + hkv) * D_ * S_;

    bf16x8 vones;
#pragma unroll
    for (int j = 0; j < 8; ++j) vones[j] = (__bf16)1.0f;

    for (int phase = 0; phase < 2; ++phase) {
        int qt = phase ? yp : (15 - yp);   // 128-query tile index
        int q0 = qt * 128;
        int qs0 = q0 + wave * 32;          // subtile s adds s*16
        int ktot = 2 * qt + 2;

        // Q fragments pre-scaled by SCALING*log2e, both subtiles
        bf16x8 qf[2][4];
#pragma unroll
        for (int s = 0; s < 2; ++s) {
            const float* qp = q + (((size_t)b * S_ + (qs0 + s * 16 + m16)) * HQ_ + hq) * D_;
#pragma unroll
            for (int c = 0; c < 4; ++c) {
                const float* p0 = qp + c * 32 + g * 8;
                bf16x8 f;
#pragma unroll
                for (int j = 0; j < 8; ++j) f[j] = (__bf16)(p0[j] * QSCALE_);
                qf[s][c] = f;
            }
        }

        f32x4 o[2][8];
#pragma unroll
        for (int s = 0; s < 2; ++s)
#pragma unroll
            for (int i = 0; i < 8; ++i) o[s][i] = (f32x4){0.f, 0.f, 0.f, 0.f};
        f32x4 o9[2];
        o9[0] = (f32x4){0.f, 0.f, 0.f, 0.f};
        o9[1] = (f32x4){0.f, 0.f, 0.f, 0.f};

        for (int kt = 0; kt < ktot; ++kt) {
            int k0 = kt * 64;
            __syncthreads();   // LDS reuse vs previous tile's readers
            // stage K tile (round-5 verbatim): row = wave*16+i*4+(lane>>4)
#pragma unroll
            for (int i = 0; i < 4; ++i) {
                int row = wave * 16 + i * 4 + (lane >> 4);
                int c = (lane & 15) ^ (row & 15);
                gl_lds16(kbase + (size_t)(k0 + row) * D_ + c * 8,
                         &ks[wave * 2048 + i * 512]);
            }
            // stage V^T tile (round-5 verbatim): d = wave*32+i*8+(lane>>3)
#pragma unroll
            for (int i = 0; i < 4; ++i) {
                int d = wave * 32 + i * 8 + (lane >> 3);
                int c = (lane & 7) ^ (d & 7);
                gl_lds16(vbase + (size_t)d * S_ + k0 + c * 8,
                         &vs[wave * 2048 + i * 512]);
            }
            __syncthreads();

            // per-subtile causal bounds (arithmetic shift floors correctly)
            int dq0 = qs0 - k0;            // local offset of sub0's first query
            int e0 = dq0 + 15;             // sub0 max query_local
            int e1 = dq0 + 31;             // sub1 max query_local
            int nmax0 = min(4, max(0, (e0 >> 4) + 1));
            int nmax1 = min(4, max(0, (e1 >> 4) + 1));
            int kc0   = min(2, max(0, (e0 >> 5) + 1));
            int kc1   = min(2, max(0, (e1 >> 5) + 1));

            // S^T[key][q] = K·Q^T: each ak read feeds both subtiles
            f32x4 sa[2][4];
#pragma unroll
            for (int s = 0; s < 2; ++s)
#pragma unroll
                for (int n = 0; n < 4; ++n) sa[s][n] = (f32x4){0.f, 0.f, 0.f, 0.f};
#pragma unroll
            for (int n = 0; n < 4; ++n) {
                if (n < nmax1) {
#pragma unroll
                    for (int c = 0; c < 4; ++c) {
                        bf16x8 ak = *(const bf16x8*)&ks[(n * 16 + m16) * 128 +
                                                        (((c * 4 + g) ^ m16) * 8)];
                        if (n < nmax0)
                            sa[0][n] = __builtin_amdgcn_mfma_f32_16x16x32_bf16(ak, qf[0][c], sa[0][n], 0, 0, 0);
                        sa[1][n] = __builtin_amdgcn_mfma_f32_16x16x32_bf16(ak, qf[1][c], sa[1][n], 0, 0, 0);
                    }
                }
            }

            // fixed-M softmax + P store per subtile (round-5 pattern)
#pragma unroll
            for (int s = 0; s < 2; ++s) {
                int nmx = s ? nmax1 : nmax0;
                int kcm = s ? kc1 : kc0;
                int dqs = dq0 + s * 16;    // local offset of subtile's first query
#pragma unroll
                for (int n = 0; n < 4; ++n) {
                    if (n < 2 * kcm) {
                        uint2 val; val.x = 0u; val.y = 0u;
                        if (n < nmx) {
                            bool needMask = (n * 16 + 15 > dqs);
                            float pr[4];
#pragma unroll
                            for (int r = 0; r < 4; ++r) {
                                float p = exp2f(sa[s][n][r]);
                                if (needMask)
                                    p = (n * 16 + g * 4 + r <= dqs + m16) ? p : 0.f;
                                pr[r] = p;
                            }
                            val.x = (unsigned int)f2bfu(pr[0]) | ((unsigned int)f2bfu(pr[1]) << 16);
                            val.y = (unsigned int)f2bfu(pr[2]) | ((unsigned int)f2bfu(pr[3]) << 16);
                        }
                        int chunk = (n * 2 + (g >> 1)) ^ m8;
                        *(uint2*)&ps[(wave * 2 + s) * 1024 + m16 * 64 + chunk * 8 + (g & 1) * 4] = val;
                    }
                }
            }
            asm volatile("s_waitcnt lgkmcnt(0)" ::: "memory");  // wave-local DS order

            // PV: each vb read feeds both subtiles; l via ones-MFMA
            bf16x8 pa[2][2];
#pragma unroll
            for (int s = 0; s < 2; ++s) {
                int kcm = s ? kc1 : kc0;
#pragma unroll
                for (int kc = 0; kc < 2; ++kc)
                    if (kc < kcm)
                        pa[s][kc] = *(const bf16x8*)&ps[(wave * 2 + s) * 1024 + m16 * 64 +
                                                        (((kc * 4 + g) ^ m8) * 8)];
            }
#pragma unroll
            for (int kc = 0; kc < 2; ++kc) {
                if (kc < kc0)
                    o9[0] = __builtin_amdgcn_mfma_f32_16x16x32_bf16(pa[0][kc], vones, o9[0], 0, 0, 0);
                if (kc < kc1)
                    o9[1] = __builtin_amdgcn_mfma_f32_16x16x32_bf16(pa[1][kc], vones, o9[1], 0, 0, 0);
            }
#pragma unroll
            for (int ds = 0; ds < 8; ++ds) {
#pragma unroll
                for (int kc = 0; kc < 2; ++kc) {
                    if (kc < kc1) {   // kc1 >= kc0 always
                        bf16x8 vb = *(const bf16x8*)&vs[(ds * 16 + m16) * 64 +
                                                        (((kc * 4 + g) ^ m8) * 8)];
                        if (kc < kc0)
                            o[0][ds] = __builtin_amdgcn_mfma_f32_16x16x32_bf16(pa[0][kc], vb, o[0][ds], 0, 0, 0);
                        o[1][ds] = __builtin_amdgcn_mfma_f32_16x16x32_bf16(pa[1][kc], vb, o[1][ds], 0, 0, 0);
                    }
                }
            }
        }

        // epilogue: O /= l (o9 rows already C-layout), write fp32
#pragma unroll
        for (int s = 0; s < 2; ++s)
#pragma unroll
            for (int r = 0; r < 4; ++r) {
                float inv = 1.f / o9[s][r];
                float* op = out + (((size_t)b * S_ + (qs0 + s * 16 + g * 4 + r)) * HQ_ + hq) * D_;
#pragma unroll
                for (int ds = 0; ds < 8; ++ds)
                    op[ds * 16 + m16] = o[s][ds][r] * inv;
            }
    }
}

extern "C" void kernel_launch(void* const* d_in, const int* in_sizes, int n_in,
                              void* d_out, int out_size, void* d_ws, size_t ws_size,
                              hipStream_t stream) {
    const float* q = (const float*)d_in[0];
    const float* k = (const float*)d_in[1];
    const float* v = (const float*)d_in[2];
    float* out = (float*)d_out;

    unsigned short* kd  = (unsigned short*)d_ws;              // 8 MB
    unsigned short* vd  = kd + (size_t)NROW_ * D_;            // 8 MB
    unsigned short* vdT = vd + (size_t)NROW_ * D_;            // 8 MB

    quant_kv<<<16384, 256, 0, stream>>>(k, v, kd, vd);
    transpose_v<<<512, 256, 0, stream>>>(vd, vdT);
    // 64 (b,hq) x 8 balanced 128-query tile pairs
    attn<<<dim3(64, 8), 256, 0, stream>>>(q, kd, vdT, out);
}